// Round 10
// baseline (378.621 us; speedup 1.0000x reference)
//
#include <hip/hip_runtime.h>
#include <hip/hip_bf16.h>

#define NN    100000
#define EE    1600000
#define INF   56
#define TFEAT 16
#define K1    72

// bucketed CSR build
#define BUCKET_BITS 10
#define BUCKET_NODES (1 << BUCKET_BITS)              // 1024 dst nodes per bucket
#define NB ((NN + BUCKET_NODES - 1) >> BUCKET_BITS)  // 98 buckets
#define BUCKET_CAP 20480                             // mean 16384, sigma ~127 -> +32 sigma
#define S1_EDGES 1024                                // edges per S1 block (4 per thread)
#define LOG2E 1.44269504f
#define MSLICE 256                                   // mean atomic slices

__device__ __forceinline__ void fatomic_add(float* p, float v) {
    __hip_atomic_fetch_add(p, v, __ATOMIC_RELAXED, __HIP_MEMORY_SCOPE_AGENT);
}

__device__ __forceinline__ float bfu2f(unsigned short u) {
    return __uint_as_float((unsigned)u << 16);
}
__device__ __forceinline__ unsigned short f2bfu(float f) {
    __hip_bfloat16 b = __float2bfloat16(f);
    return *reinterpret_cast<unsigned short*>(&b);
}
__device__ __forceinline__ float blo(unsigned u) { return __uint_as_float(u << 16); }
__device__ __forceinline__ float bhi(unsigned u) { return __uint_as_float(u & 0xFFFF0000u); }
// edge weight with s,d pre-scaled by log2e:  exp(lrelu(s+d)) = exp2(max(t, 0.2t))
__device__ __forceinline__ float ew(float t) { return exp2f(fmaxf(t, 0.2f * t)); }

// ---------------- dense feature transform (register-tiled) ----------------
template <int K, bool TEMPORAL, bool IN_BF16>
__global__ void __launch_bounds__(256) feat_kernel(
    const void* __restrict__ xin_, const float* __restrict__ temp,
    const float* __restrict__ Wt, const float* __restrict__ bt,
    const float* __restrict__ W, const float* __restrict__ asrc,
    const float* __restrict__ adst,
    __hip_bfloat16* __restrict__ h, float* __restrict__ s, float* __restrict__ d)
{
    constexpr int NPB = 64;                  // nodes per block
    constexpr int WROW = 76;                 // xc row stride (19 float4s)
    __shared__ float4 Wl4[K * 16];           // [k][li] : outs 4li..4li+3 of row k
    __shared__ __align__(16) float xc[NPB * WROW];
    const int tid = threadIdx.x;
    const int n0 = blockIdx.x * NPB;

    for (int i = tid; i < K * 16; i += 256)
        Wl4[i] = *(const float4*)&W[(i >> 4) * 64 + (i & 15) * 4];

    if (TEMPORAL) {
        const float* xin = (const float*)xin_;
        for (int i = tid; i < NPB * INF; i += 256) {
            int n = i / INF, k = i - n * INF;
            int gn = n0 + n;
            xc[n * WROW + k] = (gn < NN) ? xin[gn * INF + k] : 0.f;
        }
        for (int i = tid; i < NPB * TFEAT; i += 256) {
            int n = i >> 4, j = i & 15;
            int gn = n0 + n;
            float tv = (gn < NN) ? temp[gn] * Wt[j] + bt[j] : 0.f;
            xc[n * WROW + INF + j] = tv > 0.f ? tv : 0.f;
        }
    } else {
        const ushort4* xv4 = (const ushort4*)xin_;
        for (int i = tid; i < NPB * 16; i += 256) {
            int n = i >> 4, q = i & 15;
            int gn = n0 + n;
            float4 f = {0.f, 0.f, 0.f, 0.f};
            if (gn < NN) {
                ushort4 u = xv4[gn * 16 + q];
                f.x = bfu2f(u.x); f.y = bfu2f(u.y); f.z = bfu2f(u.z); f.w = bfu2f(u.w);
            }
            *(float4*)&xc[n * WROW + q * 4] = f;
        }
    }
    __syncthreads();

    const int w = tid >> 6, lane = tid & 63;
    const int li = lane & 15, gg = lane >> 4;
    const int nb = w * 16 + gg * 4;

    float4 a0 = {0,0,0,0}, a1 = {0,0,0,0}, a2 = {0,0,0,0}, a3 = {0,0,0,0};
    const float4* xr0 = (const float4*)&xc[(nb + 0) * WROW];
    const float4* xr1 = (const float4*)&xc[(nb + 1) * WROW];
    const float4* xr2 = (const float4*)&xc[(nb + 2) * WROW];
    const float4* xr3 = (const float4*)&xc[(nb + 3) * WROW];

#define FMA4(A, XV) \
    A.x += XV.x * w0.x + XV.y * w1.x + XV.z * w2.x + XV.w * w3.x; \
    A.y += XV.x * w0.y + XV.y * w1.y + XV.z * w2.y + XV.w * w3.y; \
    A.z += XV.x * w0.z + XV.y * w1.z + XV.z * w2.z + XV.w * w3.z; \
    A.w += XV.x * w0.w + XV.y * w1.w + XV.z * w2.w + XV.w * w3.w;

#pragma unroll
    for (int k4 = 0; k4 < K / 4; k4++) {
        float4 w0 = Wl4[(4 * k4 + 0) * 16 + li];
        float4 w1 = Wl4[(4 * k4 + 1) * 16 + li];
        float4 w2 = Wl4[(4 * k4 + 2) * 16 + li];
        float4 w3 = Wl4[(4 * k4 + 3) * 16 + li];
        float4 x0 = xr0[k4], x1 = xr1[k4], x2 = xr2[k4], x3 = xr3[k4];
        FMA4(a0, x0) FMA4(a1, x1) FMA4(a2, x2) FMA4(a3, x3)
    }
#undef FMA4

    const int head = li >> 2;
    const float4 as4 = *(const float4*)&asrc[li * 4];
    const float4 ad4 = *(const float4*)&adst[li * 4];
    float vs[4], vd[4];
    float4* ap[4] = {&a0, &a1, &a2, &a3};
#pragma unroll
    for (int j = 0; j < 4; j++) {
        float4 a = *ap[j];
        vs[j] = a.x * as4.x + a.y * as4.y + a.z * as4.z + a.w * as4.w;
        vd[j] = a.x * ad4.x + a.y * ad4.y + a.z * ad4.z + a.w * ad4.w;
        vs[j] += __shfl_xor(vs[j], 1); vs[j] += __shfl_xor(vs[j], 2);
        vd[j] += __shfl_xor(vd[j], 1); vd[j] += __shfl_xor(vd[j], 2);
    }

    ushort4* hv4 = (ushort4*)h;
#pragma unroll
    for (int j = 0; j < 4; j++) {
        int gn = n0 + nb + j;
        if (gn < NN) {
            float4 a = *ap[j];
            ushort4 st = { f2bfu(a.x), f2bfu(a.y), f2bfu(a.z), f2bfu(a.w) };
            hv4[gn * 16 + li] = st;
            if ((li & 3) == 0) {
                s[gn * 4 + head] = vs[j] * LOG2E;
                d[gn * 4 + head] = vd[j] * LOG2E;
            }
        }
    }
}

// ---------------- bucketed CSR build ----------------
__global__ void __launch_bounds__(256) csr_s1_kernel(
    const int* __restrict__ esrc, const int* __restrict__ edst,
    int* __restrict__ bucketCnt, int* __restrict__ ebuf)
{
    __shared__ int hist[NB];
    __shared__ int base[NB];
    __shared__ int loff[NB];
    const int tid = threadIdx.x;
    const int e0 = blockIdx.x * S1_EDGES;

    for (int i = tid; i < NB; i += 256) { hist[i] = 0; loff[i] = 0; }
    __syncthreads();

    int val[4], bk[4];
#pragma unroll
    for (int t = 0; t < 4; t++) {
        int e = e0 + t * 256 + tid;
        if (e < EE) {
            int sn = esrc[e], dn = edst[e];
            int b = dn >> BUCKET_BITS;
            bk[t] = b;
            val[t] = ((dn & (BUCKET_NODES - 1)) << 17) | sn;
            atomicAdd(&hist[b], 1);
        } else bk[t] = -1;
    }
    __syncthreads();
    for (int i = tid; i < NB; i += 256)
        base[i] = hist[i] ? atomicAdd(&bucketCnt[i], hist[i]) : 0;
    __syncthreads();
#pragma unroll
    for (int t = 0; t < 4; t++) {
        if (bk[t] >= 0) {
            int pos = atomicAdd(&loff[bk[t]], 1);
            ebuf[bk[t] * BUCKET_CAP + base[bk[t]] + pos] = val[t];
        }
    }
}

// S2: one block per bucket: inline csrBase scan -> LDS histogram -> block scan
// -> deg/rowptr (coalesced) -> local scatter of csr_src -> degree-sorted perm.
__global__ void __launch_bounds__(256) csr_s2_kernel(
    const int* __restrict__ bucketCnt, const int* __restrict__ ebuf,
    int* __restrict__ deg, int* __restrict__ rowptr, int* __restrict__ csr_src,
    int* __restrict__ perm)
{
    __shared__ int hist2[BUCKET_NODES];
    __shared__ int wsum[4];
    __shared__ int partial[256];
    __shared__ int dhist[64];
    __shared__ int dcur[64];
    const int b = blockIdx.x;
    const int tid = threadIdx.x;
    const int cnt = bucketCnt[b];
    const int nb0 = b << BUCKET_BITS;
    const int nnodes = min(BUCKET_NODES, NN - nb0);
    const int* seg = ebuf + b * BUCKET_CAP;

    partial[tid] = (tid < b) ? bucketCnt[tid] : 0;
    __syncthreads();
    for (int o = 128; o; o >>= 1) {
        if (tid < o) partial[tid] += partial[tid + o];
        __syncthreads();
    }
    const int cbase = partial[0];
    __syncthreads();

    for (int i = tid; i < BUCKET_NODES; i += 256) hist2[i] = 0;
    __syncthreads();
    for (int e = tid; e < cnt; e += 256) atomicAdd(&hist2[seg[e] >> 17], 1);
    __syncthreads();

    const int i0 = tid * 4;
    int h0 = hist2[i0], h1 = hist2[i0 + 1], h2 = hist2[i0 + 2], h3 = hist2[i0 + 3];
    int local = h0 + h1 + h2 + h3;
    int lane = tid & 63, wid = tid >> 6;
    int inc = local;
    for (int o = 1; o < 64; o <<= 1) {
        int u = __shfl_up(inc, o);
        if (lane >= o) inc += u;
    }
    if (lane == 63) wsum[wid] = inc;
    __syncthreads();
    int wbase = 0;
    for (int w = 0; w < wid; w++) wbase += wsum[w];
    int ebase = wbase + inc - local;
    __syncthreads();

    if (i0 < nnodes)     { deg[nb0 + i0]     = h0; rowptr[nb0 + i0]     = cbase + ebase; }
    if (i0 + 1 < nnodes) { deg[nb0 + i0 + 1] = h1; rowptr[nb0 + i0 + 1] = cbase + ebase + h0; }
    if (i0 + 2 < nnodes) { deg[nb0 + i0 + 2] = h2; rowptr[nb0 + i0 + 2] = cbase + ebase + h0 + h1; }
    if (i0 + 3 < nnodes) { deg[nb0 + i0 + 3] = h3; rowptr[nb0 + i0 + 3] = cbase + ebase + h0 + h1 + h2; }
    hist2[i0]     = ebase;
    hist2[i0 + 1] = ebase + h0;
    hist2[i0 + 2] = ebase + h0 + h1;
    hist2[i0 + 3] = ebase + h0 + h1 + h2;
    __syncthreads();

    for (int e = tid; e < cnt; e += 256) {
        int v = seg[e];
        int pos = atomicAdd(&hist2[v >> 17], 1);
        csr_src[cbase + pos] = v & 0x1FFFF;
    }

    // ---- degree-sorted permutation within this bucket (counting sort) ----
    if (tid < 64) { dhist[tid] = 0; }
    __syncthreads();
    int dkey[4] = { -1, -1, -1, -1 };
    int dv_[4] = { h0, h1, h2, h3 };
#pragma unroll
    for (int jj = 0; jj < 4; jj++) {
        if (i0 + jj < nnodes) {
            dkey[jj] = min(dv_[jj], 63);
            atomicAdd(&dhist[dkey[jj]], 1);
        }
    }
    __syncthreads();
    if (tid < 64) {
        int v = dhist[tid];
        int ic = v;
        for (int o = 1; o < 64; o <<= 1) {
            int u = __shfl_up(ic, o);
            if (tid >= o) ic += u;
        }
        dcur[tid] = ic - v;   // exclusive
    }
    __syncthreads();
#pragma unroll
    for (int jj = 0; jj < 4; jj++) {
        if (dkey[jj] >= 0) {
            int pos = atomicAdd(&dcur[dkey[jj]], 1);
            perm[nb0 + pos] = nb0 + i0 + jj;
        }
    }
}

// ---------------- fused gather-aggregate + softmax + bias + LN + ReLU (+mean) ------
// 8 channels per lane (uint4 h-gather), 8 lanes per node, 8 nodes per wave.
// No LDS, no barriers; mean via shfl-reduce + sliced atomics.
template <bool OUT_BF16>
__global__ void __launch_bounds__(256) agg_ln_kernel(
    const int* __restrict__ perm,
    const int* __restrict__ csr_src, const int* __restrict__ rowptr, const int* __restrict__ deg,
    const float* __restrict__ s, const float* __restrict__ d, const __hip_bfloat16* __restrict__ h,
    const float* __restrict__ bias, const float* __restrict__ gamma, const float* __restrict__ beta,
    void* __restrict__ out_, float* __restrict__ meanslots)
{
    const int tid = threadIdx.x;
    const int lane = tid & 63;
    const int g = lane >> 3;            // node within wave (0..7)
    const int li = lane & 7;            // channel-octet (0..7)
    const int head = li >> 1;
    const int n = blockIdx.x * 32 + (tid >> 6) * 8 + g;
    const int p = perm[n];

    const uint4* hv4 = (const uint4*)h;   // hv4[node*8 + li] = 8 bf16 channels

    const float dv = d[p * 4 + head];
    float a0, a1, a2, a3, a4, a5, a6, a7, z;
    {   // self-loop (implicit)
        float w = ew(s[p * 4 + head] + dv);
        uint4 u = hv4[p * 8 + li];
        a0 = w * blo(u.x); a1 = w * bhi(u.x);
        a2 = w * blo(u.y); a3 = w * bhi(u.y);
        a4 = w * blo(u.z); a5 = w * bhi(u.z);
        a6 = w * blo(u.w); a7 = w * bhi(u.w);
        z = w;
    }

#define ACC8(U, W) \
    a0 += W * blo(U.x); a1 += W * bhi(U.x); \
    a2 += W * blo(U.y); a3 += W * bhi(U.y); \
    a4 += W * blo(U.z); a5 += W * bhi(U.z); \
    a6 += W * blo(U.w); a7 += W * bhi(U.w);

    int j = rowptr[p];
    const int jend = j + deg[p];
    for (; j + 4 <= jend; j += 4) {      // 4-wide: batch loads, then FMAs
        int s0 = csr_src[j], s1 = csr_src[j + 1], s2 = csr_src[j + 2], s3 = csr_src[j + 3];
        float t0 = s[s0 * 4 + head], t1 = s[s1 * 4 + head];
        float t2 = s[s2 * 4 + head], t3 = s[s3 * 4 + head];
        uint4 u0 = hv4[s0 * 8 + li], u1 = hv4[s1 * 8 + li];
        uint4 u2 = hv4[s2 * 8 + li], u3 = hv4[s3 * 8 + li];
        float w0 = ew(t0 + dv), w1 = ew(t1 + dv), w2 = ew(t2 + dv), w3 = ew(t3 + dv);
        ACC8(u0, w0) ACC8(u1, w1) ACC8(u2, w2) ACC8(u3, w3)
        z += (w0 + w1) + (w2 + w3);
    }
    for (; j < jend; j++) {
        int s0 = csr_src[j];
        float w0 = ew(s[s0 * 4 + head] + dv);
        uint4 u0 = hv4[s0 * 8 + li];
        ACC8(u0, w0)
        z += w0;
    }
#undef ACC8

    const float rz = 1.f / (z + 1e-16f);
    const int c0 = li * 8;
    const float4 bv0 = *(const float4*)&bias[c0];
    const float4 bv1 = *(const float4*)&bias[c0 + 4];
    float v0 = a0 * rz + bv0.x, v1 = a1 * rz + bv0.y;
    float v2 = a2 * rz + bv0.z, v3 = a3 * rz + bv0.w;
    float v4 = a4 * rz + bv1.x, v5 = a5 * rz + bv1.y;
    float v6 = a6 * rz + bv1.z, v7 = a7 * rz + bv1.w;

    float sum = ((v0 + v1) + (v2 + v3)) + ((v4 + v5) + (v6 + v7));
    float sq  = ((v0 * v0 + v1 * v1) + (v2 * v2 + v3 * v3)) +
                ((v4 * v4 + v5 * v5) + (v6 * v6 + v7 * v7));
#pragma unroll
    for (int o = 4; o; o >>= 1) { sum += __shfl_xor(sum, o); sq += __shfl_xor(sq, o); }
    float mu = sum * (1.f / 64.f);
    float var = sq * (1.f / 64.f) - mu * mu;
    float rs = rsqrtf(var + 1e-5f);
    const float4 gv0 = *(const float4*)&gamma[c0];
    const float4 gv1 = *(const float4*)&gamma[c0 + 4];
    const float4 be0 = *(const float4*)&beta[c0];
    const float4 be1 = *(const float4*)&beta[c0 + 4];
    float y0 = (v0 - mu) * rs * gv0.x + be0.x; y0 = y0 > 0.f ? y0 : 0.f;
    float y1 = (v1 - mu) * rs * gv0.y + be0.y; y1 = y1 > 0.f ? y1 : 0.f;
    float y2 = (v2 - mu) * rs * gv0.z + be0.z; y2 = y2 > 0.f ? y2 : 0.f;
    float y3 = (v3 - mu) * rs * gv0.w + be0.w; y3 = y3 > 0.f ? y3 : 0.f;
    float y4 = (v4 - mu) * rs * gv1.x + be1.x; y4 = y4 > 0.f ? y4 : 0.f;
    float y5 = (v5 - mu) * rs * gv1.y + be1.y; y5 = y5 > 0.f ? y5 : 0.f;
    float y6 = (v6 - mu) * rs * gv1.z + be1.z; y6 = y6 > 0.f ? y6 : 0.f;
    float y7 = (v7 - mu) * rs * gv1.w + be1.w; y7 = y7 > 0.f ? y7 : 0.f;

    if (OUT_BF16) {
        uint4 st;
        st.x = (unsigned)f2bfu(y0) | ((unsigned)f2bfu(y1) << 16);
        st.y = (unsigned)f2bfu(y2) | ((unsigned)f2bfu(y3) << 16);
        st.z = (unsigned)f2bfu(y4) | ((unsigned)f2bfu(y5) << 16);
        st.w = (unsigned)f2bfu(y6) | ((unsigned)f2bfu(y7) << 16);
        ((uint4*)out_)[p * 8 + li] = st;
    } else {
        float4 st0 = { y0, y1, y2, y3 };
        float4 st1 = { y4, y5, y6, y7 };
        ((float4*)out_)[p * 16 + li * 2] = st0;
        ((float4*)out_)[p * 16 + li * 2 + 1] = st1;
        // mean: reduce over the 8 node-groups in this wave (lane bits 3..5)
        float m0 = y0, m1 = y1, m2 = y2, m3 = y3, m4 = y4, m5 = y5, m6 = y6, m7 = y7;
#pragma unroll
        for (int o = 8; o <= 32; o <<= 1) {
            m0 += __shfl_xor(m0, o); m1 += __shfl_xor(m1, o);
            m2 += __shfl_xor(m2, o); m3 += __shfl_xor(m3, o);
            m4 += __shfl_xor(m4, o); m5 += __shfl_xor(m5, o);
            m6 += __shfl_xor(m6, o); m7 += __shfl_xor(m7, o);
        }
        if (g == 0) {
            float* slot = &meanslots[(((blockIdx.x << 2) | (tid >> 6)) & (MSLICE - 1)) * 64 + c0];
            fatomic_add(slot + 0, m0); fatomic_add(slot + 1, m1);
            fatomic_add(slot + 2, m2); fatomic_add(slot + 3, m3);
            fatomic_add(slot + 4, m4); fatomic_add(slot + 5, m5);
            fatomic_add(slot + 6, m6); fatomic_add(slot + 7, m7);
        }
    }
}

// ---------------- MLP head (reduces MSLICE mean slots) ----------------
__global__ void __launch_bounds__(64) mlp_kernel(
    const float* __restrict__ meanslots,
    const float* __restrict__ Wp1, const float* __restrict__ bp1,
    const float* __restrict__ Wp2, const float* __restrict__ bp2,
    float* __restrict__ out)
{
    __shared__ float mean[64], hid[64];
    int t = threadIdx.x;
    float accm = 0.f;
#pragma unroll 8
    for (int sIdx = 0; sIdx < MSLICE; sIdx++) accm += meanslots[sIdx * 64 + t];
    mean[t] = accm * (1.f / (float)NN);
    __syncthreads();
    float acc = bp1[t];
#pragma unroll
    for (int i = 0; i < 64; i++) acc += mean[i] * Wp1[i * 64 + t];
    hid[t] = acc > 0.f ? acc : 0.f;
    __syncthreads();
    float o = bp2[t];
#pragma unroll
    for (int i = 0; i < 64; i++) o += hid[i] * Wp2[i * 64 + t];
    out[NN * 64 + t] = o;
}

extern "C" void kernel_launch(void* const* d_in, const int* in_sizes, int n_in,
                              void* d_out, int out_size, void* d_ws, size_t ws_size,
                              hipStream_t stream) {
    const float* x    = (const float*)d_in[0];
    const float* temp = (const float*)d_in[1];
    const int*   ei   = (const int*)d_in[2];
    const float* Wt   = (const float*)d_in[3];
    const float* bt   = (const float*)d_in[4];
    const float* W1   = (const float*)d_in[5];
    const float* as1  = (const float*)d_in[6];
    const float* ad1  = (const float*)d_in[7];
    const float* b1   = (const float*)d_in[8];
    const float* g1   = (const float*)d_in[9];
    const float* be1  = (const float*)d_in[10];
    const float* W2   = (const float*)d_in[11];
    const float* as2  = (const float*)d_in[12];
    const float* ad2  = (const float*)d_in[13];
    const float* b2   = (const float*)d_in[14];
    const float* g2   = (const float*)d_in[15];
    const float* be2  = (const float*)d_in[16];
    const float* Wp1  = (const float*)d_in[17];
    const float* bp1  = (const float*)d_in[18];
    const float* Wp2  = (const float*)d_in[19];
    const float* bp2  = (const float*)d_in[20];

    float* out = (float*)d_out;   // f32: x2 [100000*64] then ge [64]

    // ws layout (bytes), all offsets 256B-aligned
    char* w = (char*)d_ws;
    __hip_bfloat16* hb   = (__hip_bfloat16*)w;   w += (size_t)NN * 64 * 2;          // 12.8 MB
    __hip_bfloat16* x1b  = (__hip_bfloat16*)w;   w += (size_t)NN * 64 * 2;          // 12.8 MB
    float* sbuf    = (float*)w;                  w += (size_t)NN * 4 * 4;           // 1.6 MB
    float* dbuf    = (float*)w;                  w += (size_t)NN * 4 * 4;           // 1.6 MB
    int* bucketCnt = (int*)w;                    w += 512;
    float* meanslots = (float*)w;                w += MSLICE * 64 * 4;              // 64 KB
    int* deg       = (int*)w;                    w += (size_t)NN * 4;
    int* rowptr    = (int*)w;                    w += (size_t)NN * 4;
    int* perm      = (int*)w;                    w += (size_t)NN * 4;
    int* csr_src   = (int*)w;                    w += (size_t)EE * 4;               // 6.4 MB
    int* ebuf      = (int*)w;                    w += (size_t)NB * BUCKET_CAP * 4;  // 8 MB

    const int* esrc = ei;
    const int* edst = ei + EE;

    // single memset covers bucketCnt + meanslots (contiguous)
    hipMemsetAsync(bucketCnt, 0, 512 + MSLICE * 64 * 4, stream);

    // ---- CSR build (bucketed, L2-local) + degree-sorted perm ----
    csr_s1_kernel<<<(EE + S1_EDGES - 1) / S1_EDGES, 256, 0, stream>>>(esrc, edst, bucketCnt, ebuf);
    csr_s2_kernel<<<NB, 256, 0, stream>>>(bucketCnt, ebuf, deg, rowptr, csr_src, perm);

    const int fgrid = (NN + 63) / 64;
    const int agrid = NN / 32;   // 100000/32 = 3125 exact

    // ---- layer 1 ----
    feat_kernel<K1, true, false><<<fgrid, 256, 0, stream>>>(x, temp, Wt, bt, W1, as1, ad1, hb, sbuf, dbuf);
    agg_ln_kernel<true><<<agrid, 256, 0, stream>>>(perm, csr_src, rowptr, deg, sbuf, dbuf, hb,
                                                   b1, g1, be1, x1b, meanslots);

    // ---- layer 2 ----
    feat_kernel<64, false, true><<<fgrid, 256, 0, stream>>>(x1b, nullptr, nullptr, nullptr, W2, as2, ad2, hb, sbuf, dbuf);
    agg_ln_kernel<false><<<agrid, 256, 0, stream>>>(perm, csr_src, rowptr, deg, sbuf, dbuf, hb,
                                                    b2, g2, be2, out, meanslots);

    // ---- MLP head ----
    mlp_kernel<<<1, 64, 0, stream>>>(meanslots, Wp1, bp1, Wp2, bp2, out);
}

// Round 11
// 356.361 us; speedup vs baseline: 1.0625x; 1.0625x over previous
//
#include <hip/hip_runtime.h>
#include <hip/hip_bf16.h>

#define NN    100000
#define EE    1600000
#define INF   56
#define TFEAT 16
#define K1    72

// bucketed CSR build
#define BUCKET_BITS 10
#define BUCKET_NODES (1 << BUCKET_BITS)              // 1024 dst nodes per bucket
#define NB ((NN + BUCKET_NODES - 1) >> BUCKET_BITS)  // 98 buckets
#define BUCKET_CAP 20480                             // mean 16384, sigma ~127 -> +32 sigma
#define S1_EDGES 1024                                // edges per S1 block (4 per thread)
#define LOG2E 1.44269504f
#define MSLICE 256                                   // mean atomic slices

__device__ __forceinline__ void fatomic_add(float* p, float v) {
    __hip_atomic_fetch_add(p, v, __ATOMIC_RELAXED, __HIP_MEMORY_SCOPE_AGENT);
}

__device__ __forceinline__ float bfu2f(unsigned short u) {
    return __uint_as_float((unsigned)u << 16);
}
__device__ __forceinline__ unsigned short f2bfu(float f) {
    __hip_bfloat16 b = __float2bfloat16(f);
    return *reinterpret_cast<unsigned short*>(&b);
}
__device__ __forceinline__ float blo(unsigned u) { return __uint_as_float(u << 16); }
__device__ __forceinline__ float bhi(unsigned u) { return __uint_as_float(u & 0xFFFF0000u); }
// edge weight with s,d pre-scaled by log2e:  exp(lrelu(s+d)) = exp2(max(t, 0.2t))
__device__ __forceinline__ float ew(float t) { return exp2f(fmaxf(t, 0.2f * t)); }

// ---------------- dense feature transform (register-tiled) ----------------
template <int K, bool TEMPORAL, bool IN_BF16>
__global__ void __launch_bounds__(256) feat_kernel(
    const void* __restrict__ xin_, const float* __restrict__ temp,
    const float* __restrict__ Wt, const float* __restrict__ bt,
    const float* __restrict__ W, const float* __restrict__ asrc,
    const float* __restrict__ adst,
    __hip_bfloat16* __restrict__ h, float* __restrict__ s, float* __restrict__ d)
{
    constexpr int NPB = 64;                  // nodes per block
    constexpr int WROW = 76;                 // xc row stride (19 float4s)
    __shared__ float4 Wl4[K * 16];           // [k][li] : outs 4li..4li+3 of row k
    __shared__ __align__(16) float xc[NPB * WROW];
    const int tid = threadIdx.x;
    const int n0 = blockIdx.x * NPB;

    for (int i = tid; i < K * 16; i += 256)
        Wl4[i] = *(const float4*)&W[(i >> 4) * 64 + (i & 15) * 4];

    if (TEMPORAL) {
        const float* xin = (const float*)xin_;
        for (int i = tid; i < NPB * INF; i += 256) {
            int n = i / INF, k = i - n * INF;
            int gn = n0 + n;
            xc[n * WROW + k] = (gn < NN) ? xin[gn * INF + k] : 0.f;
        }
        for (int i = tid; i < NPB * TFEAT; i += 256) {
            int n = i >> 4, j = i & 15;
            int gn = n0 + n;
            float tv = (gn < NN) ? temp[gn] * Wt[j] + bt[j] : 0.f;
            xc[n * WROW + INF + j] = tv > 0.f ? tv : 0.f;
        }
    } else {
        const ushort4* xv4 = (const ushort4*)xin_;
        for (int i = tid; i < NPB * 16; i += 256) {
            int n = i >> 4, q = i & 15;
            int gn = n0 + n;
            float4 f = {0.f, 0.f, 0.f, 0.f};
            if (gn < NN) {
                ushort4 u = xv4[gn * 16 + q];
                f.x = bfu2f(u.x); f.y = bfu2f(u.y); f.z = bfu2f(u.z); f.w = bfu2f(u.w);
            }
            *(float4*)&xc[n * WROW + q * 4] = f;
        }
    }
    __syncthreads();

    const int w = tid >> 6, lane = tid & 63;
    const int li = lane & 15, gg = lane >> 4;
    const int nb = w * 16 + gg * 4;

    float4 a0 = {0,0,0,0}, a1 = {0,0,0,0}, a2 = {0,0,0,0}, a3 = {0,0,0,0};
    const float4* xr0 = (const float4*)&xc[(nb + 0) * WROW];
    const float4* xr1 = (const float4*)&xc[(nb + 1) * WROW];
    const float4* xr2 = (const float4*)&xc[(nb + 2) * WROW];
    const float4* xr3 = (const float4*)&xc[(nb + 3) * WROW];

#define FMA4(A, XV) \
    A.x += XV.x * w0.x + XV.y * w1.x + XV.z * w2.x + XV.w * w3.x; \
    A.y += XV.x * w0.y + XV.y * w1.y + XV.z * w2.y + XV.w * w3.y; \
    A.z += XV.x * w0.z + XV.y * w1.z + XV.z * w2.z + XV.w * w3.z; \
    A.w += XV.x * w0.w + XV.y * w1.w + XV.z * w2.w + XV.w * w3.w;

#pragma unroll
    for (int k4 = 0; k4 < K / 4; k4++) {
        float4 w0 = Wl4[(4 * k4 + 0) * 16 + li];
        float4 w1 = Wl4[(4 * k4 + 1) * 16 + li];
        float4 w2 = Wl4[(4 * k4 + 2) * 16 + li];
        float4 w3 = Wl4[(4 * k4 + 3) * 16 + li];
        float4 x0 = xr0[k4], x1 = xr1[k4], x2 = xr2[k4], x3 = xr3[k4];
        FMA4(a0, x0) FMA4(a1, x1) FMA4(a2, x2) FMA4(a3, x3)
    }
#undef FMA4

    const int head = li >> 2;
    const float4 as4 = *(const float4*)&asrc[li * 4];
    const float4 ad4 = *(const float4*)&adst[li * 4];
    float vs[4], vd[4];
    float4* ap[4] = {&a0, &a1, &a2, &a3};
#pragma unroll
    for (int j = 0; j < 4; j++) {
        float4 a = *ap[j];
        vs[j] = a.x * as4.x + a.y * as4.y + a.z * as4.z + a.w * as4.w;
        vd[j] = a.x * ad4.x + a.y * ad4.y + a.z * ad4.z + a.w * ad4.w;
        vs[j] += __shfl_xor(vs[j], 1); vs[j] += __shfl_xor(vs[j], 2);
        vd[j] += __shfl_xor(vd[j], 1); vd[j] += __shfl_xor(vd[j], 2);
    }

    ushort4* hv4 = (ushort4*)h;
#pragma unroll
    for (int j = 0; j < 4; j++) {
        int gn = n0 + nb + j;
        if (gn < NN) {
            float4 a = *ap[j];
            ushort4 st = { f2bfu(a.x), f2bfu(a.y), f2bfu(a.z), f2bfu(a.w) };
            hv4[gn * 16 + li] = st;
            if ((li & 3) == 0) {
                s[gn * 4 + head] = vs[j] * LOG2E;
                d[gn * 4 + head] = vd[j] * LOG2E;
            }
        }
    }
}

// ---------------- bucketed CSR build ----------------
__global__ void __launch_bounds__(256) csr_s1_kernel(
    const int* __restrict__ esrc, const int* __restrict__ edst,
    int* __restrict__ bucketCnt, int* __restrict__ ebuf)
{
    __shared__ int hist[NB];
    __shared__ int base[NB];
    __shared__ int loff[NB];
    const int tid = threadIdx.x;
    const int e0 = blockIdx.x * S1_EDGES;

    for (int i = tid; i < NB; i += 256) { hist[i] = 0; loff[i] = 0; }
    __syncthreads();

    int val[4], bk[4];
#pragma unroll
    for (int t = 0; t < 4; t++) {
        int e = e0 + t * 256 + tid;
        if (e < EE) {
            int sn = esrc[e], dn = edst[e];
            int b = dn >> BUCKET_BITS;
            bk[t] = b;
            val[t] = ((dn & (BUCKET_NODES - 1)) << 17) | sn;
            atomicAdd(&hist[b], 1);
        } else bk[t] = -1;
    }
    __syncthreads();
    for (int i = tid; i < NB; i += 256)
        base[i] = hist[i] ? atomicAdd(&bucketCnt[i], hist[i]) : 0;
    __syncthreads();
#pragma unroll
    for (int t = 0; t < 4; t++) {
        if (bk[t] >= 0) {
            int pos = atomicAdd(&loff[bk[t]], 1);
            ebuf[bk[t] * BUCKET_CAP + base[bk[t]] + pos] = val[t];
        }
    }
}

// S2: one block per bucket: inline csrBase scan -> LDS histogram -> block scan
//     -> deg/rowptr (coalesced) -> local scatter of csr_src.
__global__ void __launch_bounds__(256) csr_s2_kernel(
    const int* __restrict__ bucketCnt, const int* __restrict__ ebuf,
    int* __restrict__ deg, int* __restrict__ rowptr, int* __restrict__ csr_src)
{
    __shared__ int hist2[BUCKET_NODES];
    __shared__ int wsum[4];
    __shared__ int partial[256];
    const int b = blockIdx.x;
    const int tid = threadIdx.x;
    const int cnt = bucketCnt[b];
    const int nb0 = b << BUCKET_BITS;
    const int nnodes = min(BUCKET_NODES, NN - nb0);
    const int* seg = ebuf + b * BUCKET_CAP;

    partial[tid] = (tid < b) ? bucketCnt[tid] : 0;
    __syncthreads();
    for (int o = 128; o; o >>= 1) {
        if (tid < o) partial[tid] += partial[tid + o];
        __syncthreads();
    }
    const int cbase = partial[0];
    __syncthreads();

    for (int i = tid; i < BUCKET_NODES; i += 256) hist2[i] = 0;
    __syncthreads();
    for (int e = tid; e < cnt; e += 256) atomicAdd(&hist2[seg[e] >> 17], 1);
    __syncthreads();

    const int i0 = tid * 4;
    int h0 = hist2[i0], h1 = hist2[i0 + 1], h2 = hist2[i0 + 2], h3 = hist2[i0 + 3];
    int local = h0 + h1 + h2 + h3;
    int lane = tid & 63, wid = tid >> 6;
    int inc = local;
    for (int o = 1; o < 64; o <<= 1) {
        int u = __shfl_up(inc, o);
        if (lane >= o) inc += u;
    }
    if (lane == 63) wsum[wid] = inc;
    __syncthreads();
    int wbase = 0;
    for (int w = 0; w < wid; w++) wbase += wsum[w];
    int ebase = wbase + inc - local;
    __syncthreads();

    if (i0 < nnodes)     { deg[nb0 + i0]     = h0; rowptr[nb0 + i0]     = cbase + ebase; }
    if (i0 + 1 < nnodes) { deg[nb0 + i0 + 1] = h1; rowptr[nb0 + i0 + 1] = cbase + ebase + h0; }
    if (i0 + 2 < nnodes) { deg[nb0 + i0 + 2] = h2; rowptr[nb0 + i0 + 2] = cbase + ebase + h0 + h1; }
    if (i0 + 3 < nnodes) { deg[nb0 + i0 + 3] = h3; rowptr[nb0 + i0 + 3] = cbase + ebase + h0 + h1 + h2; }
    hist2[i0]     = ebase;
    hist2[i0 + 1] = ebase + h0;
    hist2[i0 + 2] = ebase + h0 + h1;
    hist2[i0 + 3] = ebase + h0 + h1 + h2;
    __syncthreads();

    for (int e = tid; e < cnt; e += 256) {
        int v = seg[e];
        int pos = atomicAdd(&hist2[v >> 17], 1);
        csr_src[cbase + pos] = v & 0x1FFFF;
    }
}

// ---------------- fused gather-aggregate + softmax + bias + LN + ReLU (+mean) ------
// 8 channels per lane (uint4 h-gather), 8 lanes per node, 8 nodes per wave,
// sequential node ids (coalesced per-node access + stores). 4-wide batched inner.
template <bool OUT_BF16>
__global__ void __launch_bounds__(256) agg_ln_kernel(
    const int* __restrict__ csr_src, const int* __restrict__ rowptr, const int* __restrict__ deg,
    const float* __restrict__ s, const float* __restrict__ d, const __hip_bfloat16* __restrict__ h,
    const float* __restrict__ bias, const float* __restrict__ gamma, const float* __restrict__ beta,
    void* __restrict__ out_, float* __restrict__ meanslots)
{
    const int tid = threadIdx.x;
    const int lane = tid & 63;
    const int g = lane >> 3;            // node within wave (0..7)
    const int li = lane & 7;            // channel-octet (0..7)
    const int head = li >> 1;
    const int n = blockIdx.x * 32 + (tid >> 6) * 8 + g;

    const uint4* hv4 = (const uint4*)h;   // hv4[node*8 + li] = 8 bf16 channels

    const float dv = d[n * 4 + head];
    float a0, a1, a2, a3, a4, a5, a6, a7, z;
    {   // self-loop (implicit)
        float w = ew(s[n * 4 + head] + dv);
        uint4 u = hv4[n * 8 + li];
        a0 = w * blo(u.x); a1 = w * bhi(u.x);
        a2 = w * blo(u.y); a3 = w * bhi(u.y);
        a4 = w * blo(u.z); a5 = w * bhi(u.z);
        a6 = w * blo(u.w); a7 = w * bhi(u.w);
        z = w;
    }

#define ACC8(U, W) \
    a0 += W * blo(U.x); a1 += W * bhi(U.x); \
    a2 += W * blo(U.y); a3 += W * bhi(U.y); \
    a4 += W * blo(U.z); a5 += W * bhi(U.z); \
    a6 += W * blo(U.w); a7 += W * bhi(U.w);

    int j = rowptr[n];
    const int jend = j + deg[n];
    for (; j + 4 <= jend; j += 4) {      // 4-wide: batch loads, then FMAs
        int s0 = csr_src[j], s1 = csr_src[j + 1], s2 = csr_src[j + 2], s3 = csr_src[j + 3];
        float t0 = s[s0 * 4 + head], t1 = s[s1 * 4 + head];
        float t2 = s[s2 * 4 + head], t3 = s[s3 * 4 + head];
        uint4 u0 = hv4[s0 * 8 + li], u1 = hv4[s1 * 8 + li];
        uint4 u2 = hv4[s2 * 8 + li], u3 = hv4[s3 * 8 + li];
        float w0 = ew(t0 + dv), w1 = ew(t1 + dv), w2 = ew(t2 + dv), w3 = ew(t3 + dv);
        ACC8(u0, w0) ACC8(u1, w1) ACC8(u2, w2) ACC8(u3, w3)
        z += (w0 + w1) + (w2 + w3);
    }
    for (; j < jend; j++) {
        int s0 = csr_src[j];
        float w0 = ew(s[s0 * 4 + head] + dv);
        uint4 u0 = hv4[s0 * 8 + li];
        ACC8(u0, w0)
        z += w0;
    }
#undef ACC8

    const float rz = 1.f / (z + 1e-16f);
    const int c0 = li * 8;
    const float4 bv0 = *(const float4*)&bias[c0];
    const float4 bv1 = *(const float4*)&bias[c0 + 4];
    float v0 = a0 * rz + bv0.x, v1 = a1 * rz + bv0.y;
    float v2 = a2 * rz + bv0.z, v3 = a3 * rz + bv0.w;
    float v4 = a4 * rz + bv1.x, v5 = a5 * rz + bv1.y;
    float v6 = a6 * rz + bv1.z, v7 = a7 * rz + bv1.w;

    float sum = ((v0 + v1) + (v2 + v3)) + ((v4 + v5) + (v6 + v7));
    float sq  = ((v0 * v0 + v1 * v1) + (v2 * v2 + v3 * v3)) +
                ((v4 * v4 + v5 * v5) + (v6 * v6 + v7 * v7));
#pragma unroll
    for (int o = 4; o; o >>= 1) { sum += __shfl_xor(sum, o); sq += __shfl_xor(sq, o); }
    float mu = sum * (1.f / 64.f);
    float var = sq * (1.f / 64.f) - mu * mu;
    float rs = rsqrtf(var + 1e-5f);
    const float4 gv0 = *(const float4*)&gamma[c0];
    const float4 gv1 = *(const float4*)&gamma[c0 + 4];
    const float4 be0 = *(const float4*)&beta[c0];
    const float4 be1 = *(const float4*)&beta[c0 + 4];
    float y0 = (v0 - mu) * rs * gv0.x + be0.x; y0 = y0 > 0.f ? y0 : 0.f;
    float y1 = (v1 - mu) * rs * gv0.y + be0.y; y1 = y1 > 0.f ? y1 : 0.f;
    float y2 = (v2 - mu) * rs * gv0.z + be0.z; y2 = y2 > 0.f ? y2 : 0.f;
    float y3 = (v3 - mu) * rs * gv0.w + be0.w; y3 = y3 > 0.f ? y3 : 0.f;
    float y4 = (v4 - mu) * rs * gv1.x + be1.x; y4 = y4 > 0.f ? y4 : 0.f;
    float y5 = (v5 - mu) * rs * gv1.y + be1.y; y5 = y5 > 0.f ? y5 : 0.f;
    float y6 = (v6 - mu) * rs * gv1.z + be1.z; y6 = y6 > 0.f ? y6 : 0.f;
    float y7 = (v7 - mu) * rs * gv1.w + be1.w; y7 = y7 > 0.f ? y7 : 0.f;

    if (OUT_BF16) {
        uint4 st;
        st.x = (unsigned)f2bfu(y0) | ((unsigned)f2bfu(y1) << 16);
        st.y = (unsigned)f2bfu(y2) | ((unsigned)f2bfu(y3) << 16);
        st.z = (unsigned)f2bfu(y4) | ((unsigned)f2bfu(y5) << 16);
        st.w = (unsigned)f2bfu(y6) | ((unsigned)f2bfu(y7) << 16);
        ((uint4*)out_)[n * 8 + li] = st;
    } else {
        float4 st0 = { y0, y1, y2, y3 };
        float4 st1 = { y4, y5, y6, y7 };
        ((float4*)out_)[n * 16 + li * 2] = st0;
        ((float4*)out_)[n * 16 + li * 2 + 1] = st1;
        // mean: reduce across the 8 node-groups in this wave (lane bits 3..5)
        float m0 = y0, m1 = y1, m2 = y2, m3 = y3, m4 = y4, m5 = y5, m6 = y6, m7 = y7;
#pragma unroll
        for (int o = 8; o <= 32; o <<= 1) {
            m0 += __shfl_xor(m0, o); m1 += __shfl_xor(m1, o);
            m2 += __shfl_xor(m2, o); m3 += __shfl_xor(m3, o);
            m4 += __shfl_xor(m4, o); m5 += __shfl_xor(m5, o);
            m6 += __shfl_xor(m6, o); m7 += __shfl_xor(m7, o);
        }
        if (g == 0) {
            float* slot = &meanslots[(((blockIdx.x << 2) | (tid >> 6)) & (MSLICE - 1)) * 64 + c0];
            fatomic_add(slot + 0, m0); fatomic_add(slot + 1, m1);
            fatomic_add(slot + 2, m2); fatomic_add(slot + 3, m3);
            fatomic_add(slot + 4, m4); fatomic_add(slot + 5, m5);
            fatomic_add(slot + 6, m6); fatomic_add(slot + 7, m7);
        }
    }
}

// ---------------- MLP head (reduces MSLICE mean slots) ----------------
__global__ void __launch_bounds__(64) mlp_kernel(
    const float* __restrict__ meanslots,
    const float* __restrict__ Wp1, const float* __restrict__ bp1,
    const float* __restrict__ Wp2, const float* __restrict__ bp2,
    float* __restrict__ out)
{
    __shared__ float mean[64], hid[64];
    int t = threadIdx.x;
    float accm = 0.f;
#pragma unroll 8
    for (int sIdx = 0; sIdx < MSLICE; sIdx++) accm += meanslots[sIdx * 64 + t];
    mean[t] = accm * (1.f / (float)NN);
    __syncthreads();
    float acc = bp1[t];
#pragma unroll
    for (int i = 0; i < 64; i++) acc += mean[i] * Wp1[i * 64 + t];
    hid[t] = acc > 0.f ? acc : 0.f;
    __syncthreads();
    float o = bp2[t];
#pragma unroll
    for (int i = 0; i < 64; i++) o += hid[i] * Wp2[i * 64 + t];
    out[NN * 64 + t] = o;
}

extern "C" void kernel_launch(void* const* d_in, const int* in_sizes, int n_in,
                              void* d_out, int out_size, void* d_ws, size_t ws_size,
                              hipStream_t stream) {
    const float* x    = (const float*)d_in[0];
    const float* temp = (const float*)d_in[1];
    const int*   ei   = (const int*)d_in[2];
    const float* Wt   = (const float*)d_in[3];
    const float* bt   = (const float*)d_in[4];
    const float* W1   = (const float*)d_in[5];
    const float* as1  = (const float*)d_in[6];
    const float* ad1  = (const float*)d_in[7];
    const float* b1   = (const float*)d_in[8];
    const float* g1   = (const float*)d_in[9];
    const float* be1  = (const float*)d_in[10];
    const float* W2   = (const float*)d_in[11];
    const float* as2  = (const float*)d_in[12];
    const float* ad2  = (const float*)d_in[13];
    const float* b2   = (const float*)d_in[14];
    const float* g2   = (const float*)d_in[15];
    const float* be2  = (const float*)d_in[16];
    const float* Wp1  = (const float*)d_in[17];
    const float* bp1  = (const float*)d_in[18];
    const float* Wp2  = (const float*)d_in[19];
    const float* bp2  = (const float*)d_in[20];

    float* out = (float*)d_out;   // f32: x2 [100000*64] then ge [64]

    // ws layout (bytes), all offsets 256B-aligned
    char* w = (char*)d_ws;
    __hip_bfloat16* hb   = (__hip_bfloat16*)w;   w += (size_t)NN * 64 * 2;          // 12.8 MB
    __hip_bfloat16* x1b  = (__hip_bfloat16*)w;   w += (size_t)NN * 64 * 2;          // 12.8 MB
    float* sbuf    = (float*)w;                  w += (size_t)NN * 4 * 4;           // 1.6 MB
    float* dbuf    = (float*)w;                  w += (size_t)NN * 4 * 4;           // 1.6 MB
    int* bucketCnt = (int*)w;                    w += 512;
    float* meanslots = (float*)w;                w += MSLICE * 64 * 4;              // 64 KB
    int* deg       = (int*)w;                    w += (size_t)NN * 4;
    int* rowptr    = (int*)w;                    w += (size_t)NN * 4;
    int* csr_src   = (int*)w;                    w += (size_t)EE * 4;               // 6.4 MB
    int* ebuf      = (int*)w;                    w += (size_t)NB * BUCKET_CAP * 4;  // 8 MB

    const int* esrc = ei;
    const int* edst = ei + EE;

    // single memset covers bucketCnt + meanslots (contiguous)
    hipMemsetAsync(bucketCnt, 0, 512 + MSLICE * 64 * 4, stream);

    // ---- CSR build (bucketed, L2-local) ----
    csr_s1_kernel<<<(EE + S1_EDGES - 1) / S1_EDGES, 256, 0, stream>>>(esrc, edst, bucketCnt, ebuf);
    csr_s2_kernel<<<NB, 256, 0, stream>>>(bucketCnt, ebuf, deg, rowptr, csr_src);

    const int fgrid = (NN + 63) / 64;
    const int agrid = NN / 32;   // 100000/32 = 3125 exact

    // ---- layer 1 ----
    feat_kernel<K1, true, false><<<fgrid, 256, 0, stream>>>(x, temp, Wt, bt, W1, as1, ad1, hb, sbuf, dbuf);
    agg_ln_kernel<true><<<agrid, 256, 0, stream>>>(csr_src, rowptr, deg, sbuf, dbuf, hb,
                                                   b1, g1, be1, x1b, meanslots);

    // ---- layer 2 ----
    feat_kernel<64, false, true><<<fgrid, 256, 0, stream>>>(x1b, nullptr, nullptr, nullptr, W2, as2, ad2, hb, sbuf, dbuf);
    agg_ln_kernel<false><<<agrid, 256, 0, stream>>>(csr_src, rowptr, deg, sbuf, dbuf, hb,
                                                    b2, g2, be2, out, meanslots);

    // ---- MLP head ----
    mlp_kernel<<<1, 64, 0, stream>>>(meanslots, Wp1, bp1, Wp2, bp2, out);
}